// Round 1
// baseline (539.462 us; speedup 1.0000x reference)
//
#include <hip/hip_runtime.h>
#include <hip/hip_bf16.h>

#define EPS 1e-5f

typedef short s8v __attribute__((ext_vector_type(8)));
typedef short s4v __attribute__((ext_vector_type(4)));
typedef float f4v __attribute__((ext_vector_type(4)));

__device__ __forceinline__ unsigned short f2bf(float f) {
  unsigned u = __builtin_bit_cast(unsigned, f);
  u = u + 0x7FFFu + ((u >> 16) & 1u);
  return (unsigned short)(u >> 16);
}
__device__ __forceinline__ float bf2f(unsigned short h) {
  unsigned u = ((unsigned)h) << 16;
  return __builtin_bit_cast(float, u);
}
__device__ __forceinline__ float fast_tanh(float x) {
  float e = __expf(2.0f * x);
  return 1.0f - 2.0f / (e + 1.0f);
}
__device__ __forceinline__ float fast_sigmoid(float x) {
  return 1.0f / (1.0f + __expf(-x));
}

// ---------------- transpose + bf16 convert: W[k][n] f32 -> WT[n][k] bf16 -----
__global__ __launch_bounds__(256) void transpose_kernel(
    const float* __restrict__ W_mq, const float* __restrict__ W_mv,
    const float* __restrict__ W_mb, unsigned short* __restrict__ W_mqT,
    unsigned short* __restrict__ W_mvT, unsigned short* __restrict__ W_mbT) {
  __shared__ float tile[32][33];
  int bid = blockIdx.x;
  const float* src; unsigned short* dst; int N, t0;
  if (bid < 64)        { src = W_mq; dst = W_mqT; N = 64;   t0 = bid; }
  else if (bid < 1088) { src = W_mv; dst = W_mvT; N = 1024; t0 = bid - 64; }
  else                 { src = W_mb; dst = W_mbT; N = 1024; t0 = bid - 1088; }
  const int K = 1024;
  int tk = t0 & 31, tn = t0 >> 5;           // 32 k-tiles per column-strip
  int k0 = tk * 32, n0 = tn * 32;
  int t = threadIdx.x;
  int cr = t >> 5, cc = t & 31;
#pragma unroll
  for (int u = 0; u < 4; u++) {
    int row = cr + u * 8;
    tile[row][cc] = src[(size_t)(k0 + row) * N + n0 + cc];
  }
  __syncthreads();
#pragma unroll
  for (int u = 0; u < 4; u++) {
    int nl = cr + u * 8;
    dst[(size_t)(n0 + nl) * K + k0 + cc] = f2bf(tile[cc][nl]);
  }
}

// ---------------- Q = dpfp(HS @ W_mq), bf16 out, all 16896 rows --------------
__global__ __launch_bounds__(256) void q_kernel(
    const float* __restrict__ HS, const unsigned short* __restrict__ W_mqT,
    unsigned short* __restrict__ Q) {
  __shared__ __align__(16) union {
    struct { unsigned short a[64 * 72]; unsigned short b[64 * 72]; } s;
    float y[64 * 65];
  } lds;
  int t = threadIdx.x;
  int r0 = blockIdx.x * 64;
  int w = t >> 6, lane = t & 63, m = lane & 15, q = lane >> 4;
  int row = t >> 2, quarter = t & 3;
  f4v acc[4] = {f4v{0,0,0,0}, f4v{0,0,0,0}, f4v{0,0,0,0}, f4v{0,0,0,0}};

  for (int kc = 0; kc < 16; kc++) {
    int k0 = kc * 64;
    // stage A: 64 rows x 64 k, f32 -> bf16
    const float* hp = HS + (size_t)(r0 + row) * 1024 + k0 + quarter * 16;
#pragma unroll
    for (int u = 0; u < 4; u++) {
      f4v hv = *(const f4v*)(hp + u * 4);
      s4v sv;
      sv[0] = (short)f2bf(hv[0]); sv[1] = (short)f2bf(hv[1]);
      sv[2] = (short)f2bf(hv[2]); sv[3] = (short)f2bf(hv[3]);
      *(s4v*)&lds.s.a[row * 72 + quarter * 16 + u * 4] = sv;
    }
    // stage B: W_mqT tile [64 n][64 k] bf16
    const unsigned short* wp = W_mqT + (size_t)row * 1024 + k0 + quarter * 16;
#pragma unroll
    for (int u = 0; u < 2; u++) {
      *(s8v*)&lds.s.b[row * 72 + quarter * 16 + u * 8] = *(const s8v*)(wp + u * 8);
    }
    __syncthreads();
#pragma unroll
    for (int ks = 0; ks < 2; ks++) {
      s8v a = *(const s8v*)&lds.s.a[(w * 16 + m) * 72 + ks * 32 + q * 8];
#pragma unroll
      for (int nf = 0; nf < 4; nf++) {
        s8v b = *(const s8v*)&lds.s.b[(nf * 16 + m) * 72 + ks * 32 + q * 8];
        acc[nf] = __builtin_amdgcn_mfma_f32_16x16x32_bf16(a, b, acc[nf], 0, 0, 0);
      }
    }
    __syncthreads();
  }
  // y to LDS (f32), then dpfp -> Q bf16
#pragma unroll
  for (int nf = 0; nf < 4; nf++)
#pragma unroll
    for (int i = 0; i < 4; i++)
      lds.y[(w * 16 + q * 4 + i) * 65 + nf * 16 + m] = acc[nf][i];
  __syncthreads();
  {
    int rr = t >> 2, part = t & 3, j0 = part * 32;
    const float* yr = &lds.y[rr * 65];
    unsigned short qbuf[32];
#pragma unroll
    for (int jj = 0; jj < 32; jj++) {
      int j = j0 + jj;
      int jm = (j + 127) & 127;
      float yv = (j < 64) ? yr[j] : -yr[j - 64];
      float x2 = fmaxf(yv, 0.f);
      float ym = (jm < 64) ? yr[jm] : -yr[jm - 64];
      float x2m = fmaxf(ym, 0.f);
      qbuf[jj] = f2bf(x2 * x2m);
    }
    unsigned short* qp = Q + (size_t)(r0 + rr) * 128 + j0;
#pragma unroll
    for (int u = 0; u < 4; u++) *(s8v*)&qp[u * 8] = *(s8v*)&qbuf[u * 8];
  }
}

// ---------------- per-segment associate: assoc, OUT, mem tokens --------------
__global__ __launch_bounds__(64) void a_kernel(
    const unsigned short* __restrict__ Q, const unsigned short* __restrict__ W_memT,
    const float* __restrict__ z, const float* __restrict__ MO,
    float* __restrict__ OUT, unsigned short* __restrict__ mem_bf, int seg) {
  int rt = blockIdx.x, ct = blockIdx.y, b = blockIdx.z;
  int lane = threadIdx.x, m = lane & 15, q = lane >> 4;
  size_t grow = (size_t)b * 4224 + seg * 528 + rt * 16;
  const unsigned short* qp = Q + (grow + m) * 128;
  const float* zp = z + b * 128 + q * 8;
  s8v a[4];
  float dp = 0.f;
#pragma unroll
  for (int ks = 0; ks < 4; ks++) {
    a[ks] = *(const s8v*)(qp + ks * 32 + q * 8);
    const float* zz = zp + ks * 32;
#pragma unroll
    for (int j = 0; j < 8; j++) dp += bf2f((unsigned short)a[ks][j]) * zz[j];
  }
  dp += __shfl_xor(dp, 16);
  dp += __shfl_xor(dp, 32);
  dp += EPS;  // den for row m, in every lane with lane&15==m

  f4v acc[4] = {f4v{0,0,0,0}, f4v{0,0,0,0}, f4v{0,0,0,0}, f4v{0,0,0,0}};
  const unsigned short* wp = W_memT + (size_t)b * 131072 + (size_t)(ct * 64 + m) * 128;
#pragma unroll
  for (int ks = 0; ks < 4; ks++) {
#pragma unroll
    for (int nf = 0; nf < 4; nf++) {
      s8v bv = *(const s8v*)(wp + nf * 2048 + ks * 32 + q * 8);
      acc[nf] = __builtin_amdgcn_mfma_f32_16x16x32_bf16(a[ks], bv, acc[nf], 0, 0, 0);
    }
  }
#pragma unroll
  for (int i = 0; i < 4; i++) {
    float den = __shfl(dp, q * 4 + i);
    int lrow = rt * 16 + q * 4 + i;
    size_t rbase = ((size_t)b * 4224 + seg * 528 + lrow) * 1024;
#pragma unroll
    for (int nf = 0; nf < 4; nf++) {
      int col = ct * 64 + nf * 16 + m;
      float assoc = acc[nf][i] / den;
      float mov = MO[rbase + col];
      OUT[rbase + col] = mov + fast_tanh(assoc);
      if (lrow >= 512) {
        mem_bf[(size_t)(b * 16 + (lrow - 512)) * 1024 + col] = f2bf(assoc + mov);
      }
    }
  }
}

// ---------------- B1: k = dpfp(mem @ W_mk), kden = k.z + EPS -----------------
__global__ __launch_bounds__(256) void b1_kernel(
    const unsigned short* __restrict__ mem_bf, const float* __restrict__ W_mk,
    const float* __restrict__ z, unsigned short* __restrict__ k_bf,
    float* __restrict__ kden) {
  int m = blockIdx.x, b = blockIdx.y;
  __shared__ float mrow[1024];
  __shared__ float part[4][64];
  int t = threadIdx.x;
  const unsigned short* mp = mem_bf + (size_t)(b * 16 + m) * 1024;
  {
    s4v v = *(const s4v*)(mp + t * 4);
#pragma unroll
    for (int j = 0; j < 4; j++) mrow[t * 4 + j] = bf2f((unsigned short)v[j]);
  }
  __syncthreads();
  int j = t & 63, kg = t >> 6;
  float p = 0.f;
  const float* wp = W_mk + j;
  for (int k = kg * 256; k < kg * 256 + 256; k += 4) {
    p += mrow[k]     * wp[(size_t)k * 64];
    p += mrow[k + 1] * wp[(size_t)(k + 1) * 64];
    p += mrow[k + 2] * wp[(size_t)(k + 2) * 64];
    p += mrow[k + 3] * wp[(size_t)(k + 3) * 64];
  }
  part[kg][j] = p;
  __syncthreads();
  if (t < 64) {
    float y = part[0][j] + part[1][j] + part[2][j] + part[3][j];
    float yprev = __shfl(y, (j + 63) & 63);   // y[j-1], j==0 -> y[63]
    float x2j   = fmaxf(y, 0.f);
    float x2j64 = fmaxf(-y, 0.f);
    float x2m1  = (j >= 1) ? fmaxf(yprev, 0.f)  : fmaxf(-yprev, 0.f);
    float x2m1b = (j >= 1) ? fmaxf(-yprev, 0.f) : fmaxf(yprev, 0.f);
    float kj = x2j * x2m1;
    float kj64 = x2j64 * x2m1b;
    k_bf[(size_t)(b * 16 + m) * 128 + j] = f2bf(kj);
    k_bf[(size_t)(b * 16 + m) * 128 + 64 + j] = f2bf(kj64);
    float p2 = kj * z[b * 128 + j] + kj64 * z[b * 128 + 64 + j];
#pragma unroll
    for (int off = 32; off > 0; off >>= 1) p2 += __shfl_xor(p2, off);
    if (j == 0) kden[b * 16 + m] = p2 + EPS;
  }
}

// ---------------- B2: v/gate/prev, delta-rule W_mem update, z update ---------
__global__ __launch_bounds__(256) void b2_kernel(
    const unsigned short* __restrict__ mem_bf,
    const unsigned short* __restrict__ W_mvT, const unsigned short* __restrict__ W_mbT,
    const unsigned short* __restrict__ k_bf, const float* __restrict__ kden,
    const float* __restrict__ b_mb, float* __restrict__ W_mem,
    unsigned short* __restrict__ W_memT, float* __restrict__ z) {
  int ct = blockIdx.x, b = blockIdx.y;
  __shared__ __align__(16) unsigned short k_lds[16 * 128];
  __shared__ float ni_lds[16 * 65];
  int t = threadIdx.x;
  *(s8v*)&k_lds[t * 8] = *(const s8v*)(k_bf + (size_t)b * 2048 + t * 8);
  __syncthreads();
  int w = t >> 6, lane = t & 63, m = lane & 15, q = lane >> 4;
  int c = ct * 64 + w * 16 + m;
  const unsigned short* ap = mem_bf + (size_t)(b * 16 + m) * 1024;
  const unsigned short* bvp = W_mvT + (size_t)c * 1024;
  const unsigned short* bgp = W_mbT + (size_t)c * 1024;
  f4v accv = {0,0,0,0}, accg = {0,0,0,0}, accp = {0,0,0,0};
  for (int ks = 0; ks < 32; ks++) {
    s8v a = *(const s8v*)(ap + ks * 32 + q * 8);
    s8v bv = *(const s8v*)(bvp + ks * 32 + q * 8);
    s8v bg = *(const s8v*)(bgp + ks * 32 + q * 8);
    accv = __builtin_amdgcn_mfma_f32_16x16x32_bf16(a, bv, accv, 0, 0, 0);
    accg = __builtin_amdgcn_mfma_f32_16x16x32_bf16(a, bg, accg, 0, 0, 0);
  }
  const unsigned short* kp = k_bf + (size_t)(b * 16 + m) * 128;
  const unsigned short* bmp = W_memT + (size_t)b * 131072 + (size_t)c * 128;
#pragma unroll
  for (int ks = 0; ks < 4; ks++) {
    s8v a = *(const s8v*)(kp + ks * 32 + q * 8);
    s8v bm = *(const s8v*)(bmp + ks * 32 + q * 8);
    accp = __builtin_amdgcn_mfma_f32_16x16x32_bf16(a, bm, accp, 0, 0, 0);
  }
  float bmb = b_mb[c];
#pragma unroll
  for (int i = 0; i < 4; i++) {
    int mr = q * 4 + i;
    float kd = kden[b * 16 + mr];
    float prev = accp[i] / kd;
    float g = fast_sigmoid(accg[i] + bmb);
    ni_lds[mr * 65 + (w * 16 + m)] = g * (accv[i] - prev);
  }
  __syncthreads();
  int cl = t & 63, kg = t >> 6;
  int cc = ct * 64 + cl;
  float* wmp = W_mem + (size_t)b * 131072 + cc;
  unsigned short* wtp = W_memT + (size_t)b * 131072 + (size_t)cc * 128;
  for (int kk8 = 0; kk8 < 4; kk8++) {
    int kkb = kg * 32 + kk8 * 8;
    s8v pack;
#pragma unroll
    for (int u = 0; u < 8; u++) {
      int kk = kkb + u;
      float delta = 0.f;
#pragma unroll
      for (int mm = 0; mm < 16; mm++)
        delta += bf2f(k_lds[mm * 128 + kk]) * ni_lds[mm * 65 + cl];
      float nv = wmp[(size_t)kk * 1024] + delta;
      wmp[(size_t)kk * 1024] = nv;
      pack[u] = (short)f2bf(nv);
    }
    *(s8v*)&wtp[kkb] = pack;
  }
  if (ct == 0 && t < 128) {
    float s = 0.f;
#pragma unroll
    for (int mm = 0; mm < 16; mm++) s += bf2f(k_lds[mm * 128 + t]);
    z[b * 128 + t] += s;
  }
}

extern "C" void kernel_launch(void* const* d_in, const int* in_sizes, int n_in,
                              void* d_out, int out_size, void* d_ws, size_t ws_size,
                              hipStream_t stream) {
  const float* HS  = (const float*)d_in[0];
  const float* MO  = (const float*)d_in[1];
  const float* W_mq = (const float*)d_in[2];
  const float* W_mk = (const float*)d_in[3];
  const float* W_mv = (const float*)d_in[4];
  const float* W_mb = (const float*)d_in[5];
  const float* b_mb = (const float*)d_in[6];
  float* OUT = (float*)d_out;

  char* wsb = (char*)d_ws;
  float*          W_mem  = (float*)(wsb + 0);               // 2,097,152 B
  unsigned short* W_memT = (unsigned short*)(wsb + 2097152); // 1,048,576 B
  float*          zbuf   = (float*)(wsb + 3145728);          // 2,048 B
  unsigned short* Qb     = (unsigned short*)(wsb + 3147776); // 4,325,376 B
  unsigned short* W_mqT  = (unsigned short*)(wsb + 7473152); // 131,072 B
  unsigned short* W_mvT  = (unsigned short*)(wsb + 7604224); // 2,097,152 B
  unsigned short* W_mbT  = (unsigned short*)(wsb + 9701376); // 2,097,152 B
  unsigned short* mem_bf = (unsigned short*)(wsb + 11798528);// 131,072 B
  unsigned short* k_bf   = (unsigned short*)(wsb + 11929600);// 16,384 B
  float*          kdenb  = (float*)(wsb + 11945984);         // 256 B

  // zero W_mem, W_memT, z (contiguous prefix)
  hipMemsetAsync(wsb, 0, 3147776, stream);
  transpose_kernel<<<2112, 256, 0, stream>>>(W_mq, W_mv, W_mb, W_mqT, W_mvT, W_mbT);
  q_kernel<<<264, 256, 0, stream>>>(HS, W_mqT, Qb);
  for (int s = 0; s < 8; s++) {
    a_kernel<<<dim3(33, 16, 4), 64, 0, stream>>>(Qb, W_memT, zbuf, MO, OUT, mem_bf, s);
    b1_kernel<<<dim3(16, 4), 256, 0, stream>>>(mem_bf, W_mk, zbuf, k_bf, kdenb);
    b2_kernel<<<dim3(16, 4), 256, 0, stream>>>(mem_bf, W_mvT, W_mbT, k_bf, kdenb,
                                               b_mb, W_mem, W_memT, zbuf);
  }
}

// Round 3
// 491.166 us; speedup vs baseline: 1.0983x; 1.0983x over previous
//
#include <hip/hip_runtime.h>
#include <hip/hip_bf16.h>

#define EPS 1e-5f

typedef short s8v __attribute__((ext_vector_type(8)));
typedef short s4v __attribute__((ext_vector_type(4)));
typedef float f4v __attribute__((ext_vector_type(4)));

__device__ __forceinline__ unsigned short f2bf(float f) {
  unsigned u = __builtin_bit_cast(unsigned, f);
  u = u + 0x7FFFu + ((u >> 16) & 1u);
  return (unsigned short)(u >> 16);
}
__device__ __forceinline__ float bf2f(unsigned short h) {
  unsigned u = ((unsigned)h) << 16;
  return __builtin_bit_cast(float, u);
}
__device__ __forceinline__ float fast_tanh(float x) {
  float e = __expf(2.0f * x);
  return 1.0f - 2.0f / (e + 1.0f);
}
__device__ __forceinline__ float fast_sigmoid(float x) {
  return 1.0f / (1.0f + __expf(-x));
}

// ------ transpose + bf16: W[k][n] f32 -> WT[n][k] bf16 (mq, mk, mv, mb) ------
__global__ __launch_bounds__(256) void transpose_kernel(
    const float* __restrict__ W_mq, const float* __restrict__ W_mk,
    const float* __restrict__ W_mv, const float* __restrict__ W_mb,
    unsigned short* __restrict__ W_mqT, unsigned short* __restrict__ W_mkT,
    unsigned short* __restrict__ W_mvT, unsigned short* __restrict__ W_mbT) {
  __shared__ float tile[32][33];
  int bid = blockIdx.x;
  const float* src; unsigned short* dst; int N, t0;
  if (bid < 64)        { src = W_mq; dst = W_mqT; N = 64;   t0 = bid; }
  else if (bid < 128)  { src = W_mk; dst = W_mkT; N = 64;   t0 = bid - 64; }
  else if (bid < 1152) { src = W_mv; dst = W_mvT; N = 1024; t0 = bid - 128; }
  else                 { src = W_mb; dst = W_mbT; N = 1024; t0 = bid - 1152; }
  const int K = 1024;
  int tk = t0 & 31, tn = t0 >> 5;
  int k0 = tk * 32, n0 = tn * 32;
  int t = threadIdx.x;
  int cr = t >> 5, cc = t & 31;
#pragma unroll
  for (int u = 0; u < 4; u++) {
    int row = cr + u * 8;
    tile[row][cc] = src[(size_t)(k0 + row) * N + n0 + cc];
  }
  __syncthreads();
#pragma unroll
  for (int u = 0; u < 4; u++) {
    int nl = cr + u * 8;
    dst[(size_t)(n0 + nl) * K + k0 + cc] = f2bf(tile[cc][nl]);
  }
}

// ------ Q = dpfp(HS @ W_mq): direct-fragment, 2-way K-split, no staging LDS --
__global__ __launch_bounds__(128) void q_kernel(
    const float* __restrict__ HS, const unsigned short* __restrict__ W_mqT,
    unsigned short* __restrict__ Q) {
  __shared__ __align__(16) union { float y[16 * 64]; unsigned short kq[16 * 128]; } lds;
  int t = threadIdx.x, wv = t >> 6, lane = t & 63, m = lane & 15, q = lane >> 4;
  int r0 = blockIdx.x * 16;
  const float* ap = HS + (size_t)(r0 + m) * 1024 + wv * 512 + q * 8;
  const unsigned short* bp = W_mqT + (size_t)m * 1024 + wv * 512 + q * 8;
  f4v acc[4] = {f4v{0,0,0,0}, f4v{0,0,0,0}, f4v{0,0,0,0}, f4v{0,0,0,0}};
#pragma unroll 4
  for (int ks = 0; ks < 16; ks++) {
    int k0 = ks * 32;
    f4v h0 = *(const f4v*)(ap + k0);
    f4v h1 = *(const f4v*)(ap + k0 + 4);
    s8v a;
    a[0] = (short)f2bf(h0[0]); a[1] = (short)f2bf(h0[1]);
    a[2] = (short)f2bf(h0[2]); a[3] = (short)f2bf(h0[3]);
    a[4] = (short)f2bf(h1[0]); a[5] = (short)f2bf(h1[1]);
    a[6] = (short)f2bf(h1[2]); a[7] = (short)f2bf(h1[3]);
#pragma unroll
    for (int nf = 0; nf < 4; nf++) {
      s8v b = *(const s8v*)(bp + nf * 16384 + k0);
      acc[nf] = __builtin_amdgcn_mfma_f32_16x16x32_bf16(a, b, acc[nf], 0, 0, 0);
    }
  }
  if (wv == 1) {
#pragma unroll
    for (int nf = 0; nf < 4; nf++)
#pragma unroll
      for (int i = 0; i < 4; i++)
        lds.y[(nf * 4 + i) * 64 + lane] = acc[nf][i];
  }
  __syncthreads();
  if (wv == 0) {
#pragma unroll
    for (int nf = 0; nf < 4; nf++)
#pragma unroll
      for (int i = 0; i < 4; i++)
        acc[nf][i] += lds.y[(nf * 4 + i) * 64 + lane];
    int srcl = (lane & 48) | ((m + 15) & 15);
#pragma unroll
    for (int i = 0; i < 4; i++) {
      float yp[4];
#pragma unroll
      for (int nf = 0; nf < 4; nf++) yp[nf] = __shfl(acc[nf][i], srcl);
      int r = q * 4 + i;
#pragma unroll
      for (int nf = 0; nf < 4; nf++) {
        float yv = acc[nf][i];
        float py = (m != 0) ? yp[nf] : (nf > 0 ? yp[nf - 1] : yp[3]);
        bool wrap = (m == 0 && nf == 0);
        float x2lo = wrap ? fmaxf(-py, 0.f) : fmaxf(py, 0.f);
        float x2hi = wrap ? fmaxf(py, 0.f) : fmaxf(-py, 0.f);
        lds.kq[r * 128 + nf * 16 + m]      = f2bf(fmaxf(yv, 0.f) * x2lo);
        lds.kq[r * 128 + 64 + nf * 16 + m] = f2bf(fmaxf(-yv, 0.f) * x2hi);
      }
    }
  }
  __syncthreads();
  // coalesced copy LDS -> Q, all 128 threads
  {
    int row = t >> 3, ch = t & 7;
    unsigned short* qp = Q + (size_t)(r0 + row) * 128 + ch * 16;
    *(s8v*)(qp)     = *(const s8v*)&lds.kq[row * 128 + ch * 16];
    *(s8v*)(qp + 8) = *(const s8v*)&lds.kq[row * 128 + ch * 16 + 8];
  }
}

// ------ assoc tile: 16 rows x 64 cols against a (W_memT, z) snapshot --------
__device__ __forceinline__ void assoc_tile(
    const unsigned short* __restrict__ Qb, const unsigned short* __restrict__ WmemT_s,
    const float* __restrict__ z_s, const float* __restrict__ MO,
    float* __restrict__ OUT, unsigned short* __restrict__ mem_bf,
    int seg, int rt, int ct, int b, bool write_mem) {
  int lane = threadIdx.x & 63, m = lane & 15, q = lane >> 4;
  size_t grow = (size_t)b * 4224 + seg * 528 + rt * 16;
  const unsigned short* qp = Qb + (grow + m) * 128;
  const float* zp = z_s + b * 128 + q * 8;
  s8v a[4];
  float dp = 0.f;
#pragma unroll
  for (int ks = 0; ks < 4; ks++) {
    a[ks] = *(const s8v*)(qp + ks * 32 + q * 8);
    f4v z0 = *(const f4v*)(zp + ks * 32);
    f4v z1 = *(const f4v*)(zp + ks * 32 + 4);
#pragma unroll
    for (int j = 0; j < 4; j++) dp += bf2f((unsigned short)a[ks][j]) * z0[j];
#pragma unroll
    for (int j = 0; j < 4; j++) dp += bf2f((unsigned short)a[ks][j + 4]) * z1[j];
  }
  dp += __shfl_xor(dp, 16);
  dp += __shfl_xor(dp, 32);
  dp += EPS;
  f4v acc[4] = {f4v{0,0,0,0}, f4v{0,0,0,0}, f4v{0,0,0,0}, f4v{0,0,0,0}};
  const unsigned short* wp = WmemT_s + ((size_t)b * 1024 + ct * 64 + m) * 128;
#pragma unroll
  for (int ks = 0; ks < 4; ks++) {
#pragma unroll
    for (int nf = 0; nf < 4; nf++) {
      s8v bv = *(const s8v*)(wp + nf * 2048 + ks * 32 + q * 8);
      acc[nf] = __builtin_amdgcn_mfma_f32_16x16x32_bf16(a[ks], bv, acc[nf], 0, 0, 0);
    }
  }
#pragma unroll
  for (int i = 0; i < 4; i++) {
    float den = __shfl(dp, q * 4 + i);
    int lrow = rt * 16 + q * 4 + i;
    size_t rbase = ((size_t)b * 4224 + seg * 528 + lrow) * 1024;
#pragma unroll
    for (int nf = 0; nf < 4; nf++) {
      int col = ct * 64 + nf * 16 + m;
      float assoc = acc[nf][i] / den;
      float mov = MO[rbase + col];
      OUT[rbase + col] = mov + fast_tanh(assoc);
      if (write_mem)
        mem_bf[(size_t)(b * 16 + (lrow - 512)) * 1024 + col] = f2bf(assoc + mov);
    }
  }
}

// serial-path: only the 16 memory-token rows of segment `seg`
__global__ __launch_bounds__(64) void a_mem_kernel(
    const unsigned short* __restrict__ Qb, const unsigned short* __restrict__ WmemT_s,
    const float* __restrict__ z_s, const float* __restrict__ MO,
    float* __restrict__ OUT, unsigned short* __restrict__ mem_bf, int seg) {
  assoc_tile(Qb, WmemT_s, z_s, MO, OUT, mem_bf, seg, 32, blockIdx.x, blockIdx.y, true);
}

// deferred bulk: rows 0..511 of every segment, against stored snapshots
__global__ __launch_bounds__(64) void a_bulk_kernel(
    const unsigned short* __restrict__ Qb, const unsigned short* __restrict__ hist,
    const float* __restrict__ zh, const float* __restrict__ MO,
    float* __restrict__ OUT) {
  int seg = blockIdx.z >> 2, b = blockIdx.z & 3;
  assoc_tile(Qb, hist + (size_t)seg * 524288, zh + seg * 512, MO, OUT, nullptr,
             seg, blockIdx.x, blockIdx.y, b, false);
}

// ------ fused update: k=dpfp(mem@W_mk), kden, v/gate/prev, delta-rule, z -----
__global__ __launch_bounds__(256) void update_kernel(
    const unsigned short* __restrict__ mem_bf, const unsigned short* __restrict__ W_mkT,
    const unsigned short* __restrict__ W_mvT, const unsigned short* __restrict__ W_mbT,
    const float* __restrict__ z_s, const unsigned short* __restrict__ WmemT_s,
    const float* __restrict__ b_mb, float* __restrict__ W_mem,
    unsigned short* __restrict__ WmemT_next, float* __restrict__ z_next) {
  int ct = blockIdx.x, b = blockIdx.y;
  __shared__ float y_lds[16 * 64];
  __shared__ __align__(16) float k_f[16 * 128];
  __shared__ __align__(16) unsigned short k_bf[16 * 128];
  __shared__ float part[256];
  __shared__ float kden_l[16];
  __shared__ float ni_lds[16 * 65];
  int t = threadIdx.x, wv = t >> 6, lane = t & 63, m = lane & 15, q = lane >> 4;
  const unsigned short* ap = mem_bf + (size_t)(b * 16 + m) * 1024;
  // phase 1: y = mem @ W_mkT  (wave wv -> cols wv*16..+16)
  {
    const unsigned short* bp = W_mkT + (size_t)(wv * 16 + m) * 1024;
    f4v acy = {0, 0, 0, 0};
    for (int ks = 0; ks < 32; ks++) {
      s8v av = *(const s8v*)(ap + ks * 32 + q * 8);
      s8v bv = *(const s8v*)(bp + ks * 32 + q * 8);
      acy = __builtin_amdgcn_mfma_f32_16x16x32_bf16(av, bv, acy, 0, 0, 0);
    }
#pragma unroll
    for (int i = 0; i < 4; i++) y_lds[(q * 4 + i) * 64 + wv * 16 + m] = acy[i];
  }
  __syncthreads();
  // phase 2: k = dpfp(y), kden partials
  {
    int r = t >> 4, jg = t & 15;
    const float* yr = &y_lds[r * 64];
    const float* zz = z_s + b * 128;
    float pd = 0.f;
#pragma unroll
    for (int u = 0; u < 8; u++) {
      int jj = jg * 8 + u, jm = (jj + 127) & 127;
      float yj = (jj < 64) ? yr[jj] : -yr[jj - 64];
      float ym = (jm < 64) ? yr[jm] : -yr[jm - 64];
      float kv = fmaxf(yj, 0.f) * fmaxf(ym, 0.f);
      k_f[r * 128 + jj] = kv;
      k_bf[r * 128 + jj] = f2bf(kv);
      pd += kv * zz[jj];
    }
    part[t] = pd;
  }
  __syncthreads();
  if (t < 16) {
    float s = 0.f;
#pragma unroll
    for (int jg = 0; jg < 16; jg++) s += part[t * 16 + jg];
    kden_l[t] = s + EPS;
  }
  __syncthreads();
  // phase 3: v, gate, prev for cols c
  int c = ct * 64 + wv * 16 + m;
  f4v accv = {0,0,0,0}, accg = {0,0,0,0}, accp = {0,0,0,0};
  {
    const unsigned short* bvp = W_mvT + (size_t)c * 1024;
    const unsigned short* bgp = W_mbT + (size_t)c * 1024;
    for (int ks = 0; ks < 32; ks++) {
      s8v av = *(const s8v*)(ap + ks * 32 + q * 8);
      s8v bv = *(const s8v*)(bvp + ks * 32 + q * 8);
      s8v bg = *(const s8v*)(bgp + ks * 32 + q * 8);
      accv = __builtin_amdgcn_mfma_f32_16x16x32_bf16(av, bv, accv, 0, 0, 0);
      accg = __builtin_amdgcn_mfma_f32_16x16x32_bf16(av, bg, accg, 0, 0, 0);
    }
    const unsigned short* bmp = WmemT_s + ((size_t)b * 1024 + c) * 128;
#pragma unroll
    for (int ks = 0; ks < 4; ks++) {
      s8v ak = *(const s8v*)&k_bf[m * 128 + ks * 32 + q * 8];
      s8v bm = *(const s8v*)(bmp + ks * 32 + q * 8);
      accp = __builtin_amdgcn_mfma_f32_16x16x32_bf16(ak, bm, accp, 0, 0, 0);
    }
  }
  float bmb = b_mb[c];
#pragma unroll
  for (int i = 0; i < 4; i++) {
    int r = q * 4 + i;
    float prev = accp[i] / kden_l[r];
    float g = fast_sigmoid(accg[i] + bmb);
    ni_lds[r * 65 + wv * 16 + m] = g * (accv[i] - prev);
  }
  __syncthreads();
  // phase 4: W_mem += k^T @ ni ; emit bf16 snapshot; z update
  int cl = t & 63, kg = t >> 6, cc = ct * 64 + cl;
  float niv[16];
#pragma unroll
  for (int mm = 0; mm < 16; mm++) niv[mm] = ni_lds[mm * 65 + cl];
  float delta[32];
#pragma unroll
  for (int jj = 0; jj < 32; jj++) delta[jj] = 0.f;
#pragma unroll
  for (int mm = 0; mm < 16; mm++) {
    const float* kb = &k_f[mm * 128 + kg * 32];
    float nv = niv[mm];
#pragma unroll
    for (int ch = 0; ch < 8; ch++) {
      f4v kv4 = *(const f4v*)(kb + ch * 4);
#pragma unroll
      for (int jj = 0; jj < 4; jj++) delta[ch * 4 + jj] += kv4[jj] * nv;
    }
  }
  float* wmp = W_mem + (size_t)b * 131072 + cc;
  unsigned short* wtp = WmemT_next + ((size_t)b * 1024 + cc) * 128 + kg * 32;
#pragma unroll
  for (int c8 = 0; c8 < 4; c8++) {
    s8v pk;
#pragma unroll
    for (int u = 0; u < 8; u++) {
      int kk = kg * 32 + c8 * 8 + u;
      float nv = wmp[(size_t)kk * 1024] + delta[c8 * 8 + u];
      wmp[(size_t)kk * 1024] = nv;
      pk[u] = (short)f2bf(nv);
    }
    *(s8v*)(wtp + c8 * 8) = pk;
  }
  if (ct == 0 && t < 128) {
    float s = 0.f;
#pragma unroll
    for (int r = 0; r < 16; r++) s += k_f[r * 128 + t];
    z_next[b * 128 + t] = z_s[b * 128 + t] + s;
  }
}

extern "C" void kernel_launch(void* const* d_in, const int* in_sizes, int n_in,
                              void* d_out, int out_size, void* d_ws, size_t ws_size,
                              hipStream_t stream) {
  const float* HS  = (const float*)d_in[0];
  const float* MO  = (const float*)d_in[1];
  const float* W_mq = (const float*)d_in[2];
  const float* W_mk = (const float*)d_in[3];
  const float* W_mv = (const float*)d_in[4];
  const float* W_mb = (const float*)d_in[5];
  const float* b_mb = (const float*)d_in[6];
  float* OUT = (float*)d_out;

  char* wsb = (char*)d_ws;
  float*          W_mem  = (float*)(wsb + 0);                 //  2,097,152
  unsigned short* hist   = (unsigned short*)(wsb + 2097152);  //  9 x 1,048,576
  float*          zh     = (float*)(wsb + 11534336);          //  9 x 2,048
  unsigned short* Qb     = (unsigned short*)(wsb + 11552768); //  4,325,376
  unsigned short* W_mqT  = (unsigned short*)(wsb + 15878144); //  131,072
  unsigned short* W_mkT  = (unsigned short*)(wsb + 16009216); //  131,072
  unsigned short* W_mvT  = (unsigned short*)(wsb + 16140288); //  2,097,152
  unsigned short* W_mbT  = (unsigned short*)(wsb + 18237440); //  2,097,152
  unsigned short* mem_bf = (unsigned short*)(wsb + 20334592); //  131,072
  // total ~20.47 MB

  (void)hipMemsetAsync(wsb, 0, 3145728, stream);            // W_mem + hist slot 0
  (void)hipMemsetAsync(wsb + 11534336, 0, 2048, stream);    // z slot 0
  transpose_kernel<<<2176, 256, 0, stream>>>(W_mq, W_mk, W_mv, W_mb,
                                             W_mqT, W_mkT, W_mvT, W_mbT);
  q_kernel<<<1056, 128, 0, stream>>>(HS, W_mqT, Qb);
  for (int s = 0; s < 8; s++) {
    const unsigned short* hs = hist + (size_t)s * 524288;
    unsigned short* hn = hist + (size_t)(s + 1) * 524288;
    const float* zs = zh + s * 512;
    float* zn = zh + (s + 1) * 512;
    a_mem_kernel<<<dim3(16, 4), 64, 0, stream>>>(Qb, hs, zs, MO, OUT, mem_bf, s);
    update_kernel<<<dim3(16, 4), 256, 0, stream>>>(mem_bf, W_mkT, W_mvT, W_mbT,
                                                   zs, hs, b_mb, W_mem, hn, zn);
  }
  a_bulk_kernel<<<dim3(32, 16, 32), 64, 0, stream>>>(Qb, hist, zh, MO, OUT);
}

// Round 4
// 467.070 us; speedup vs baseline: 1.1550x; 1.0516x over previous
//
#include <hip/hip_runtime.h>
#include <hip/hip_bf16.h>

#define EPS 1e-5f
#define NBLK 64

typedef short s8v __attribute__((ext_vector_type(8)));
typedef short s4v __attribute__((ext_vector_type(4)));
typedef float f4v __attribute__((ext_vector_type(4)));

__device__ __forceinline__ unsigned short f2bf(float f) {
  unsigned u = __builtin_bit_cast(unsigned, f);
  u = u + 0x7FFFu + ((u >> 16) & 1u);
  return (unsigned short)(u >> 16);
}
__device__ __forceinline__ float bf2f(unsigned short h) {
  unsigned u = ((unsigned)h) << 16;
  return __builtin_bit_cast(float, u);
}
__device__ __forceinline__ float fast_tanh(float x) {
  float e = __expf(2.0f * x);
  return 1.0f - 2.0f / (e + 1.0f);
}
__device__ __forceinline__ float fast_sigmoid(float x) {
  return 1.0f / (1.0f + __expf(-x));
}
__device__ __forceinline__ float frcp(float x) { return __builtin_amdgcn_rcpf(x); }

// ------ transpose + bf16: W[k][n] f32 -> WT[n][k] bf16 (mq, mk, mv, mb) ------
__global__ __launch_bounds__(256) void transpose_kernel(
    const float* __restrict__ W_mq, const float* __restrict__ W_mk,
    const float* __restrict__ W_mv, const float* __restrict__ W_mb,
    unsigned short* __restrict__ W_mqT, unsigned short* __restrict__ W_mkT,
    unsigned short* __restrict__ W_mvT, unsigned short* __restrict__ W_mbT) {
  __shared__ float tile[32][33];
  int bid = blockIdx.x;
  const float* src; unsigned short* dst; int N, t0;
  if (bid < 64)        { src = W_mq; dst = W_mqT; N = 64;   t0 = bid; }
  else if (bid < 128)  { src = W_mk; dst = W_mkT; N = 64;   t0 = bid - 64; }
  else if (bid < 1152) { src = W_mv; dst = W_mvT; N = 1024; t0 = bid - 128; }
  else                 { src = W_mb; dst = W_mbT; N = 1024; t0 = bid - 1152; }
  const int K = 1024;
  int tk = t0 & 31, tn = t0 >> 5;
  int k0 = tk * 32, n0 = tn * 32;
  int t = threadIdx.x;
  int cr = t >> 5, cc = t & 31;
#pragma unroll
  for (int u = 0; u < 4; u++) {
    int row = cr + u * 8;
    tile[row][cc] = src[(size_t)(k0 + row) * N + n0 + cc];
  }
  __syncthreads();
#pragma unroll
  for (int u = 0; u < 4; u++) {
    int nl = cr + u * 8;
    dst[(size_t)(n0 + nl) * K + k0 + cc] = f2bf(tile[cc][nl]);
  }
}

// ------ Q = dpfp(HS @ W_mq): direct-fragment, 2-way K-split -----------------
__global__ __launch_bounds__(128) void q_kernel(
    const float* __restrict__ HS, const unsigned short* __restrict__ W_mqT,
    unsigned short* __restrict__ Q) {
  __shared__ __align__(16) union { float y[16 * 64]; unsigned short kq[16 * 128]; } lds;
  int t = threadIdx.x, wv = t >> 6, lane = t & 63, m = lane & 15, q = lane >> 4;
  int r0 = blockIdx.x * 16;
  const float* ap = HS + (size_t)(r0 + m) * 1024 + wv * 512 + q * 8;
  const unsigned short* bp = W_mqT + (size_t)m * 1024 + wv * 512 + q * 8;
  f4v acc[4] = {f4v{0,0,0,0}, f4v{0,0,0,0}, f4v{0,0,0,0}, f4v{0,0,0,0}};
#pragma unroll 4
  for (int ks = 0; ks < 16; ks++) {
    int k0 = ks * 32;
    f4v h0 = *(const f4v*)(ap + k0);
    f4v h1 = *(const f4v*)(ap + k0 + 4);
    s8v a;
    a[0] = (short)f2bf(h0[0]); a[1] = (short)f2bf(h0[1]);
    a[2] = (short)f2bf(h0[2]); a[3] = (short)f2bf(h0[3]);
    a[4] = (short)f2bf(h1[0]); a[5] = (short)f2bf(h1[1]);
    a[6] = (short)f2bf(h1[2]); a[7] = (short)f2bf(h1[3]);
#pragma unroll
    for (int nf = 0; nf < 4; nf++) {
      s8v b = *(const s8v*)(bp + nf * 16384 + k0);
      acc[nf] = __builtin_amdgcn_mfma_f32_16x16x32_bf16(a, b, acc[nf], 0, 0, 0);
    }
  }
  if (wv == 1) {
#pragma unroll
    for (int nf = 0; nf < 4; nf++)
#pragma unroll
      for (int i = 0; i < 4; i++)
        lds.y[(nf * 4 + i) * 64 + lane] = acc[nf][i];
  }
  __syncthreads();
  if (wv == 0) {
#pragma unroll
    for (int nf = 0; nf < 4; nf++)
#pragma unroll
      for (int i = 0; i < 4; i++)
        acc[nf][i] += lds.y[(nf * 4 + i) * 64 + lane];
    int srcl = (lane & 48) | ((m + 15) & 15);
#pragma unroll
    for (int i = 0; i < 4; i++) {
      float yp[4];
#pragma unroll
      for (int nf = 0; nf < 4; nf++) yp[nf] = __shfl(acc[nf][i], srcl);
      int r = q * 4 + i;
#pragma unroll
      for (int nf = 0; nf < 4; nf++) {
        float yv = acc[nf][i];
        float py = (m != 0) ? yp[nf] : (nf > 0 ? yp[nf - 1] : yp[3]);
        bool wrap = (m == 0 && nf == 0);
        float x2lo = wrap ? fmaxf(-py, 0.f) : fmaxf(py, 0.f);
        float x2hi = wrap ? fmaxf(py, 0.f) : fmaxf(-py, 0.f);
        lds.kq[r * 128 + nf * 16 + m]      = f2bf(fmaxf(yv, 0.f) * x2lo);
        lds.kq[r * 128 + 64 + nf * 16 + m] = f2bf(fmaxf(-yv, 0.f) * x2hi);
      }
    }
  }
  __syncthreads();
  {
    int row = t >> 3, ch = t & 7;
    unsigned short* qp = Q + (size_t)(r0 + row) * 128 + ch * 16;
    *(s8v*)(qp)     = *(const s8v*)&lds.kq[row * 128 + ch * 16];
    *(s8v*)(qp + 8) = *(const s8v*)&lds.kq[row * 128 + ch * 16 + 8];
  }
}

// ------ persistent scan: whole 8-segment recurrence in ONE dispatch ----------
// 64 blocks (ct=0..15 x b=0..3), each owns W_mem cols [ct*64, ct*64+64) in LDS.
__global__ __launch_bounds__(256, 1) void scan_kernel(
    const unsigned short* __restrict__ Qb, const unsigned short* __restrict__ W_mkT,
    const unsigned short* __restrict__ W_mvT, const unsigned short* __restrict__ W_mbT,
    const float* __restrict__ b_mb, const float* __restrict__ MO,
    float* __restrict__ OUT, unsigned short* __restrict__ hist,
    float* __restrict__ zh, unsigned short* __restrict__ mem_bf, int* bar) {
  __shared__ float Wf[128 * 64];                            // f32 master [k][c]
  __shared__ __align__(16) unsigned short Wbf[64 * 132];    // bf16 [c][k], pad 132
  __shared__ __align__(16) unsigned short mem_l[16 * 1032]; // mem rows, pad 1032
  __shared__ float y_lds[16 * 64];
  __shared__ __align__(16) float k_f[16 * 128];
  __shared__ __align__(16) unsigned short k_bf[16 * 128];
  __shared__ float part[256];
  __shared__ float kden_l[16];
  __shared__ float ni_lds[16 * 65];
  __shared__ float z_l[128];

  int t = threadIdx.x, wv = t >> 6, lane = t & 63, m = lane & 15, q = lane >> 4;
  int ct = blockIdx.x & 15, b = blockIdx.x >> 4;

  // zero state
  for (int i = t; i < 128 * 64; i += 256) Wf[i] = 0.f;
  for (int i = t; i < 64 * 132; i += 256) Wbf[i] = 0;
  if (t < 128) z_l[t] = 0.f;
  __syncthreads();

  for (int s = 0; s < 8; s++) {
    // ---- phase A: snapshot dump + mem-token assoc ----
    {
      int col = t >> 2, koff = (t & 3) * 32;
      const unsigned short* srcp = &Wbf[col * 132 + koff];
      unsigned short* dstp = hist + (size_t)s * 524288 +
                             ((size_t)b * 1024 + ct * 64 + col) * 128 + koff;
#pragma unroll
      for (int u = 0; u < 4; u++) *(s8v*)(dstp + u * 8) = *(const s8v*)(srcp + u * 8);
      if (ct == 0 && t < 128) zh[s * 512 + b * 128 + t] = z_l[t];
    }
    {
      size_t grow = (size_t)b * 4224 + s * 528 + 512;
      const unsigned short* qp = Qb + (grow + m) * 128;
      s8v a[4];
      float dp = 0.f;
#pragma unroll
      for (int ks = 0; ks < 4; ks++) {
        a[ks] = *(const s8v*)(qp + ks * 32 + q * 8);
#pragma unroll
        for (int j = 0; j < 8; j++)
          dp += bf2f((unsigned short)a[ks][j]) * z_l[ks * 32 + q * 8 + j];
      }
      dp += __shfl_xor(dp, 16);
      dp += __shfl_xor(dp, 32);
      dp += EPS;
      f4v acc = {0, 0, 0, 0};
#pragma unroll
      for (int ks = 0; ks < 4; ks++) {
        s8v bv = *(const s8v*)&Wbf[(wv * 16 + m) * 132 + ks * 32 + q * 8];
        acc = __builtin_amdgcn_mfma_f32_16x16x32_bf16(a[ks], bv, acc, 0, 0, 0);
      }
      unsigned short* mb = mem_bf + (s & 1) * 65536;
#pragma unroll
      for (int i = 0; i < 4; i++) {
        float rden = frcp(__shfl(dp, q * 4 + i));
        int col = ct * 64 + wv * 16 + m;
        size_t rbase = (grow + q * 4 + i) * 1024;
        float assoc = acc[i] * rden;
        float mov = MO[rbase + col];
        OUT[rbase + col] = mov + fast_tanh(assoc);
        mb[(size_t)(b * 16 + q * 4 + i) * 1024 + col] = f2bf(assoc + mov);
      }
    }
    // ---- grid barrier (device-scope) ----
    __syncthreads();
    if (t == 0) {
      __threadfence();
      atomicAdd(bar + s, 1);
      while (atomicAdd(bar + s, 0) < NBLK) __builtin_amdgcn_s_sleep(2);
      __threadfence();
    }
    __syncthreads();
    // ---- stage full mem rows for batch b into LDS ----
    {
      const unsigned short* srcp = mem_bf + (s & 1) * 65536 + b * 16384;
      int r = t >> 4, c0 = (t & 15) * 64;
#pragma unroll
      for (int u = 0; u < 8; u++)
        *(s8v*)&mem_l[r * 1032 + c0 + u * 8] = *(const s8v*)(srcp + r * 1024 + c0 + u * 8);
    }
    __syncthreads();
    // ---- phase 1: y = mem @ W_mkT ----
    {
      const unsigned short* ap2 = &mem_l[m * 1032];
      const unsigned short* bp = W_mkT + (size_t)(wv * 16 + m) * 1024;
      f4v acy = {0, 0, 0, 0};
      for (int ks = 0; ks < 32; ks++) {
        s8v av = *(const s8v*)(ap2 + ks * 32 + q * 8);
        s8v bv = *(const s8v*)(bp + ks * 32 + q * 8);
        acy = __builtin_amdgcn_mfma_f32_16x16x32_bf16(av, bv, acy, 0, 0, 0);
      }
#pragma unroll
      for (int i = 0; i < 4; i++) y_lds[(q * 4 + i) * 64 + wv * 16 + m] = acy[i];
    }
    __syncthreads();
    // ---- phase 2: k = dpfp(y), kden partials ----
    {
      int r = t >> 4, jg = t & 15;
      const float* yr = &y_lds[r * 64];
      float pd = 0.f;
#pragma unroll
      for (int u = 0; u < 8; u++) {
        int jj = jg * 8 + u, jm = (jj + 127) & 127;
        float yj = (jj < 64) ? yr[jj] : -yr[jj - 64];
        float ym = (jm < 64) ? yr[jm] : -yr[jm - 64];
        float kv = fmaxf(yj, 0.f) * fmaxf(ym, 0.f);
        k_f[r * 128 + jj] = kv;
        k_bf[r * 128 + jj] = f2bf(kv);
        pd += kv * z_l[jj];
      }
      part[t] = pd;
    }
    __syncthreads();
    if (t < 16) {
      float ssum = 0.f;
#pragma unroll
      for (int jg = 0; jg < 16; jg++) ssum += part[t * 16 + jg];
      kden_l[t] = ssum + EPS;
    }
    __syncthreads();
    // ---- phase 3: v, gate, prev ----
    {
      int c = ct * 64 + wv * 16 + m;
      const unsigned short* ap2 = &mem_l[m * 1032];
      const unsigned short* bvp = W_mvT + (size_t)c * 1024;
      const unsigned short* bgp = W_mbT + (size_t)c * 1024;
      f4v accv = {0,0,0,0}, accg = {0,0,0,0}, accp = {0,0,0,0};
      for (int ks = 0; ks < 32; ks++) {
        s8v av = *(const s8v*)(ap2 + ks * 32 + q * 8);
        s8v bv = *(const s8v*)(bvp + ks * 32 + q * 8);
        s8v bg = *(const s8v*)(bgp + ks * 32 + q * 8);
        accv = __builtin_amdgcn_mfma_f32_16x16x32_bf16(av, bv, accv, 0, 0, 0);
        accg = __builtin_amdgcn_mfma_f32_16x16x32_bf16(av, bg, accg, 0, 0, 0);
      }
#pragma unroll
      for (int ks = 0; ks < 4; ks++) {
        s8v ak = *(const s8v*)&k_bf[m * 128 + ks * 32 + q * 8];
        s8v bm = *(const s8v*)&Wbf[(wv * 16 + m) * 132 + ks * 32 + q * 8];
        accp = __builtin_amdgcn_mfma_f32_16x16x32_bf16(ak, bm, accp, 0, 0, 0);
      }
      float bmb = b_mb[c];
#pragma unroll
      for (int i = 0; i < 4; i++) {
        int r = q * 4 + i;
        float prev = accp[i] * frcp(kden_l[r]);
        float g = fast_sigmoid(accg[i] + bmb);
        ni_lds[r * 65 + wv * 16 + m] = g * (accv[i] - prev);
      }
    }
    __syncthreads();
    // ---- phase 4: W += k^T @ ni (LDS f32 + bf16), z += sum k ----
    {
      int cl = t & 63, kg = t >> 6;
      float niv[16];
#pragma unroll
      for (int mm = 0; mm < 16; mm++) niv[mm] = ni_lds[mm * 65 + cl];
      float delta[32];
#pragma unroll
      for (int jj = 0; jj < 32; jj++) delta[jj] = 0.f;
#pragma unroll
      for (int mm = 0; mm < 16; mm++) {
        const float* kb = &k_f[mm * 128 + kg * 32];
        float nv = niv[mm];
#pragma unroll
        for (int ch = 0; ch < 8; ch++) {
          f4v kv4 = *(const f4v*)(kb + ch * 4);
#pragma unroll
          for (int jj = 0; jj < 4; jj++) delta[ch * 4 + jj] += kv4[jj] * nv;
        }
      }
#pragma unroll
      for (int c8 = 0; c8 < 4; c8++) {
        s8v pk;
#pragma unroll
        for (int u = 0; u < 8; u++) {
          int kk = kg * 32 + c8 * 8 + u;
          float nv = Wf[kk * 64 + cl] + delta[c8 * 8 + u];
          Wf[kk * 64 + cl] = nv;
          pk[u] = (short)f2bf(nv);
        }
        *(s8v*)&Wbf[cl * 132 + kg * 32 + c8 * 8] = pk;
      }
      if (t < 128) {
        float ssum = 0.f;
#pragma unroll
        for (int r = 0; r < 16; r++) ssum += k_f[r * 128 + t];
        z_l[t] += ssum;
      }
    }
    __syncthreads();
  }
}

// ------ deferred bulk assoc: 64x64 tiles, float4 MO/OUT epilogue -------------
__global__ __launch_bounds__(256) void a_bulk_kernel(
    const unsigned short* __restrict__ Qb, const unsigned short* __restrict__ hist,
    const float* __restrict__ zh, const float* __restrict__ MO,
    float* __restrict__ OUT) {
  __shared__ float as_l[64 * 65];
  int t = threadIdx.x, wv = t >> 6, lane = t & 63, m = lane & 15, q = lane >> 4;
  int rt4 = blockIdx.x, ct = blockIdx.y;
  int seg = blockIdx.z >> 2, b = blockIdx.z & 3;
  const unsigned short* Wm = hist + (size_t)seg * 524288 + ((size_t)b * 1024 + ct * 64) * 128;
  const float* zp = zh + seg * 512 + b * 128;
  size_t grow = (size_t)b * 4224 + seg * 528 + rt4 * 64 + wv * 16;
  const unsigned short* qp = Qb + (grow + m) * 128;
  s8v a[4];
  float dp = 0.f;
#pragma unroll
  for (int ks = 0; ks < 4; ks++) {
    a[ks] = *(const s8v*)(qp + ks * 32 + q * 8);
    f4v z0 = *(const f4v*)(zp + ks * 32 + q * 8);
    f4v z1 = *(const f4v*)(zp + ks * 32 + q * 8 + 4);
#pragma unroll
    for (int j = 0; j < 4; j++) dp += bf2f((unsigned short)a[ks][j]) * z0[j];
#pragma unroll
    for (int j = 0; j < 4; j++) dp += bf2f((unsigned short)a[ks][j + 4]) * z1[j];
  }
  dp += __shfl_xor(dp, 16);
  dp += __shfl_xor(dp, 32);
  dp += EPS;
  f4v acc[4] = {f4v{0,0,0,0}, f4v{0,0,0,0}, f4v{0,0,0,0}, f4v{0,0,0,0}};
#pragma unroll
  for (int ks = 0; ks < 4; ks++) {
#pragma unroll
    for (int nf = 0; nf < 4; nf++) {
      s8v bv = *(const s8v*)(Wm + (size_t)(nf * 16 + m) * 128 + ks * 32 + q * 8);
      acc[nf] = __builtin_amdgcn_mfma_f32_16x16x32_bf16(a[ks], bv, acc[nf], 0, 0, 0);
    }
  }
#pragma unroll
  for (int i = 0; i < 4; i++) {
    float rden = frcp(__shfl(dp, q * 4 + i));
#pragma unroll
    for (int nf = 0; nf < 4; nf++)
      as_l[(wv * 16 + q * 4 + i) * 65 + nf * 16 + m] = acc[nf][i] * rden;
  }
  __syncthreads();
  {
    int r = t >> 2, cchunk = (t & 3) * 16;
    size_t rbase = ((size_t)b * 4224 + seg * 528 + rt4 * 64 + r) * 1024 + ct * 64 + cchunk;
    const float* ar = &as_l[r * 65 + cchunk];
#pragma unroll
    for (int u = 0; u < 4; u++) {
      f4v mo = *(const f4v*)(MO + rbase + u * 4);
      f4v o;
#pragma unroll
      for (int j = 0; j < 4; j++) o[j] = mo[j] + fast_tanh(ar[u * 4 + j]);
      *(f4v*)(OUT + rbase + u * 4) = o;
    }
  }
}

extern "C" void kernel_launch(void* const* d_in, const int* in_sizes, int n_in,
                              void* d_out, int out_size, void* d_ws, size_t ws_size,
                              hipStream_t stream) {
  const float* HS  = (const float*)d_in[0];
  const float* MO  = (const float*)d_in[1];
  const float* W_mq = (const float*)d_in[2];
  const float* W_mk = (const float*)d_in[3];
  const float* W_mv = (const float*)d_in[4];
  const float* W_mb = (const float*)d_in[5];
  const float* b_mb = (const float*)d_in[6];
  float* OUT = (float*)d_out;

  char* wsb = (char*)d_ws;
  unsigned short* hist   = (unsigned short*)(wsb + 0);        // 8 x 1,048,576
  float*          zh     = (float*)(wsb + 8388608);           // 8 x 2,048
  unsigned short* Qb     = (unsigned short*)(wsb + 8404992);  // 4,325,376
  unsigned short* W_mqT  = (unsigned short*)(wsb + 12730368); // 131,072
  unsigned short* W_mkT  = (unsigned short*)(wsb + 12861440); // 131,072
  unsigned short* W_mvT  = (unsigned short*)(wsb + 12992512); // 2,097,152
  unsigned short* W_mbT  = (unsigned short*)(wsb + 15089664); // 2,097,152
  unsigned short* mem_bf = (unsigned short*)(wsb + 17186816); // 2 x 131,072
  int*            bar    = (int*)(wsb + 17448960);            // 64 B
  // total ~17.45 MB

  (void)hipMemsetAsync(bar, 0, 64, stream);
  transpose_kernel<<<2176, 256, 0, stream>>>(W_mq, W_mk, W_mv, W_mb,
                                             W_mqT, W_mkT, W_mvT, W_mbT);
  q_kernel<<<1056, 128, 0, stream>>>(HS, W_mqT, Qb);
  scan_kernel<<<NBLK, 256, 0, stream>>>(Qb, W_mkT, W_mvT, W_mbT, b_mb, MO, OUT,
                                        hist, zh, mem_bf, bar);
  a_bulk_kernel<<<dim3(8, 16, 32), 256, 0, stream>>>(Qb, hist, zh, MO, OUT);
}

// Round 5
// 464.888 us; speedup vs baseline: 1.1604x; 1.0047x over previous
//
#include <hip/hip_runtime.h>
#include <hip/hip_bf16.h>

#define EPS 1e-5f

typedef short s8v __attribute__((ext_vector_type(8)));
typedef short s4v __attribute__((ext_vector_type(4)));
typedef float f4v __attribute__((ext_vector_type(4)));

__device__ __forceinline__ unsigned short f2bf(float f) {
  unsigned u = __builtin_bit_cast(unsigned, f);
  u = u + 0x7FFFu + ((u >> 16) & 1u);
  return (unsigned short)(u >> 16);
}
__device__ __forceinline__ float bf2f(unsigned short h) {
  unsigned u = ((unsigned)h) << 16;
  return __builtin_bit_cast(float, u);
}
__device__ __forceinline__ float fast_tanh(float x) {
  float e = __expf(2.0f * x);
  return 1.0f - 2.0f / (e + 1.0f);
}
__device__ __forceinline__ float fast_sigmoid(float x) {
  return 1.0f / (1.0f + __expf(-x));
}
__device__ __forceinline__ float frcp(float x) { return __builtin_amdgcn_rcpf(x); }

// ------ transpose + bf16: W[k][n] f32 -> WT[n][k] bf16 (mq, mk, mv, mb) ------
__global__ __launch_bounds__(256) void transpose_kernel(
    const float* __restrict__ W_mq, const float* __restrict__ W_mk,
    const float* __restrict__ W_mv, const float* __restrict__ W_mb,
    unsigned short* __restrict__ W_mqT, unsigned short* __restrict__ W_mkT,
    unsigned short* __restrict__ W_mvT, unsigned short* __restrict__ W_mbT) {
  __shared__ float tile[32][33];
  int bid = blockIdx.x;
  const float* src; unsigned short* dst; int N, t0;
  if (bid < 64)        { src = W_mq; dst = W_mqT; N = 64;   t0 = bid; }
  else if (bid < 128)  { src = W_mk; dst = W_mkT; N = 64;   t0 = bid - 64; }
  else if (bid < 1152) { src = W_mv; dst = W_mvT; N = 1024; t0 = bid - 128; }
  else                 { src = W_mb; dst = W_mbT; N = 1024; t0 = bid - 1152; }
  const int K = 1024;
  int tk = t0 & 31, tn = t0 >> 5;
  int k0 = tk * 32, n0 = tn * 32;
  int t = threadIdx.x;
  int cr = t >> 5, cc = t & 31;
#pragma unroll
  for (int u = 0; u < 4; u++) {
    int row = cr + u * 8;
    tile[row][cc] = src[(size_t)(k0 + row) * N + n0 + cc];
  }
  __syncthreads();
#pragma unroll
  for (int u = 0; u < 4; u++) {
    int nl = cr + u * 8;
    dst[(size_t)(n0 + nl) * K + k0 + cc] = f2bf(tile[cc][nl]);
  }
}

// ------ Q = dpfp(HS @ W_mq): direct-fragment, 2-way K-split -----------------
__global__ __launch_bounds__(128) void q_kernel(
    const float* __restrict__ HS, const unsigned short* __restrict__ W_mqT,
    unsigned short* __restrict__ Q) {
  __shared__ __align__(16) union { float y[16 * 64]; unsigned short kq[16 * 128]; } lds;
  int t = threadIdx.x, wv = t >> 6, lane = t & 63, m = lane & 15, q = lane >> 4;
  int r0 = blockIdx.x * 16;
  const float* ap = HS + (size_t)(r0 + m) * 1024 + wv * 512 + q * 8;
  const unsigned short* bp = W_mqT + (size_t)m * 1024 + wv * 512 + q * 8;
  f4v acc[4] = {f4v{0,0,0,0}, f4v{0,0,0,0}, f4v{0,0,0,0}, f4v{0,0,0,0}};
#pragma unroll 4
  for (int ks = 0; ks < 16; ks++) {
    int k0 = ks * 32;
    f4v h0 = *(const f4v*)(ap + k0);
    f4v h1 = *(const f4v*)(ap + k0 + 4);
    s8v a;
    a[0] = (short)f2bf(h0[0]); a[1] = (short)f2bf(h0[1]);
    a[2] = (short)f2bf(h0[2]); a[3] = (short)f2bf(h0[3]);
    a[4] = (short)f2bf(h1[0]); a[5] = (short)f2bf(h1[1]);
    a[6] = (short)f2bf(h1[2]); a[7] = (short)f2bf(h1[3]);
#pragma unroll
    for (int nf = 0; nf < 4; nf++) {
      s8v b = *(const s8v*)(bp + nf * 16384 + k0);
      acc[nf] = __builtin_amdgcn_mfma_f32_16x16x32_bf16(a, b, acc[nf], 0, 0, 0);
    }
  }
  if (wv == 1) {
#pragma unroll
    for (int nf = 0; nf < 4; nf++)
#pragma unroll
      for (int i = 0; i < 4; i++)
        lds.y[(nf * 4 + i) * 64 + lane] = acc[nf][i];
  }
  __syncthreads();
  if (wv == 0) {
#pragma unroll
    for (int nf = 0; nf < 4; nf++)
#pragma unroll
      for (int i = 0; i < 4; i++)
        acc[nf][i] += lds.y[(nf * 4 + i) * 64 + lane];
    int srcl = (lane & 48) | ((m + 15) & 15);
#pragma unroll
    for (int i = 0; i < 4; i++) {
      float yp[4];
#pragma unroll
      for (int nf = 0; nf < 4; nf++) yp[nf] = __shfl(acc[nf][i], srcl);
      int r = q * 4 + i;
#pragma unroll
      for (int nf = 0; nf < 4; nf++) {
        float yv = acc[nf][i];
        float py = (m != 0) ? yp[nf] : (nf > 0 ? yp[nf - 1] : yp[3]);
        bool wrap = (m == 0 && nf == 0);
        float x2lo = wrap ? fmaxf(-py, 0.f) : fmaxf(py, 0.f);
        float x2hi = wrap ? fmaxf(py, 0.f) : fmaxf(-py, 0.f);
        lds.kq[r * 128 + nf * 16 + m]      = f2bf(fmaxf(yv, 0.f) * x2lo);
        lds.kq[r * 128 + 64 + nf * 16 + m] = f2bf(fmaxf(-yv, 0.f) * x2hi);
      }
    }
  }
  __syncthreads();
  {
    int row = t >> 3, ch = t & 7;
    unsigned short* qp = Q + (size_t)(r0 + row) * 128 + ch * 16;
    *(s8v*)(qp)     = *(const s8v*)&lds.kq[row * 128 + ch * 16];
    *(s8v*)(qp + 8) = *(const s8v*)&lds.kq[row * 128 + ch * 16 + 8];
  }
}

// ------ persistent scan: whole 8-segment recurrence in ONE dispatch ----------
// 64 blocks (ct 0..15 x b 0..3); block owns W_mem cols [ct*64, ct*64+64) in LDS.
__global__ __launch_bounds__(256, 1) void scan_kernel(
    const unsigned short* __restrict__ Qb, const unsigned short* __restrict__ W_mkT,
    const unsigned short* __restrict__ W_mvT, const unsigned short* __restrict__ W_mbT,
    const float* __restrict__ b_mb, const float* __restrict__ MO,
    float* __restrict__ OUT, unsigned short* __restrict__ hist,
    float* __restrict__ zh, unsigned short* __restrict__ mem_bf, int* bar) {
  __shared__ float Wf[128 * 64];                         // f32 master [k][c]
  __shared__ __align__(16) unsigned short Wbf[64 * 132]; // bf16 [c][k], pad 132
  __shared__ float y_lds[16 * 64];
  __shared__ __align__(16) float k_f[16 * 128];
  __shared__ __align__(16) unsigned short k_bf[16 * 136];
  __shared__ float kden_l[16];
  __shared__ float ni_lds[16 * 65];
  __shared__ float z_l[128];

  int t = threadIdx.x, wv = t >> 6, lane = t & 63, m = lane & 15, q = lane >> 4;
  int ct = blockIdx.x & 15, b = blockIdx.x >> 4;
  int col = ct * 64 + wv * 16 + m;

  for (int i = t; i < 128 * 64; i += 256) Wf[i] = 0.f;
  for (int i = t; i < 64 * 132; i += 256) Wbf[i] = 0;
  if (t < 128) z_l[t] = 0.f;
  float bmb = b_mb[col];
  __syncthreads();

  // prefetch phase-A operands for segment 0
  s8v aq[4]; float mo_pf[4];
  {
    const unsigned short* qp = Qb + ((size_t)b * 4224 + 512 + m) * 128;
#pragma unroll
    for (int ks = 0; ks < 4; ks++) aq[ks] = *(const s8v*)(qp + ks * 32 + q * 8);
    const float* mop = MO + ((size_t)b * 4224 + 512 + q * 4) * 1024 + col;
#pragma unroll
    for (int i = 0; i < 4; i++) mo_pf[i] = mop[(size_t)i * 1024];
  }

  for (int s = 0; s < 8; s++) {
    // ---- phase A: mem-token assoc from registers + LDS state ----
    {
      float dp = 0.f;
#pragma unroll
      for (int ks = 0; ks < 4; ks++)
#pragma unroll
        for (int j = 0; j < 8; j++)
          dp += bf2f((unsigned short)aq[ks][j]) * z_l[ks * 32 + q * 8 + j];
      dp += __shfl_xor(dp, 16);
      dp += __shfl_xor(dp, 32);
      dp += EPS;
      f4v acc = {0, 0, 0, 0};
#pragma unroll
      for (int ks = 0; ks < 4; ks++) {
        s8v bv = *(const s8v*)&Wbf[(wv * 16 + m) * 132 + ks * 32 + q * 8];
        acc = __builtin_amdgcn_mfma_f32_16x16x32_bf16(aq[ks], bv, acc, 0, 0, 0);
      }
      unsigned short* mb = mem_bf + (s & 1) * 65536 + b * 16384;
      size_t grow = (size_t)b * 4224 + s * 528 + 512;
#pragma unroll
      for (int i = 0; i < 4; i++) {
        float rden = frcp(__shfl(dp, q * 4 + i));
        float assoc = acc[i] * rden;
        float mov = mo_pf[i];
        OUT[(grow + q * 4 + i) * 1024 + col] = mov + fast_tanh(assoc);
        mb[(q * 4 + i) * 1024 + col] = f2bf(assoc + mov);
      }
    }
    // ---- per-b grid barrier (16 blocks) ----
    __syncthreads();
    if (t == 0) {
      __threadfence();
      atomicAdd(bar + s * 4 + b, 1);
      while (__hip_atomic_load(bar + s * 4 + b, __ATOMIC_RELAXED,
                               __HIP_MEMORY_SCOPE_AGENT) < 16)
        __builtin_amdgcn_s_sleep(1);
      __threadfence();
    }
    __syncthreads();
    // ---- merged loop: y = mem@W_mkT, v = mem@W_mvT, g = mem@W_mbT ----
    f4v accv = {0,0,0,0}, accg = {0,0,0,0};
    {
      const unsigned short* avp = mem_bf + (s & 1) * 65536 + b * 16384 + m * 1024 + q * 8;
      const unsigned short* bkp = W_mkT + (size_t)(wv * 16 + m) * 1024 + q * 8;
      const unsigned short* bvp = W_mvT + (size_t)col * 1024 + q * 8;
      const unsigned short* bgp = W_mbT + (size_t)col * 1024 + q * 8;
      f4v acy = {0, 0, 0, 0};
#pragma unroll 4
      for (int ks = 0; ks < 32; ks++) {
        s8v av = *(const s8v*)(avp + ks * 32);
        s8v bk = *(const s8v*)(bkp + ks * 32);
        s8v bv = *(const s8v*)(bvp + ks * 32);
        s8v bg = *(const s8v*)(bgp + ks * 32);
        acy  = __builtin_amdgcn_mfma_f32_16x16x32_bf16(av, bk, acy, 0, 0, 0);
        accv = __builtin_amdgcn_mfma_f32_16x16x32_bf16(av, bv, accv, 0, 0, 0);
        accg = __builtin_amdgcn_mfma_f32_16x16x32_bf16(av, bg, accg, 0, 0, 0);
      }
#pragma unroll
      for (int i = 0; i < 4; i++) y_lds[(q * 4 + i) * 64 + wv * 16 + m] = acy[i];
    }
    __syncthreads();
    // ---- k = dpfp(y), kden via 16-lane shfl reduction ----
    {
      int r = t >> 4, jg = t & 15;
      const float* yr = &y_lds[r * 64];
      float pd = 0.f;
#pragma unroll
      for (int u = 0; u < 8; u++) {
        int jj = jg * 8 + u, jm = (jj + 127) & 127;
        float yj = (jj < 64) ? yr[jj] : -yr[jj - 64];
        float ym = (jm < 64) ? yr[jm] : -yr[jm - 64];
        float kv = fmaxf(yj, 0.f) * fmaxf(ym, 0.f);
        k_f[r * 128 + jj] = kv;
        k_bf[r * 136 + jj] = f2bf(kv);
        pd += kv * z_l[jj];
      }
      pd += __shfl_xor(pd, 1);
      pd += __shfl_xor(pd, 2);
      pd += __shfl_xor(pd, 4);
      pd += __shfl_xor(pd, 8);
      if (jg == 0) kden_l[r] = pd + EPS;
    }
    __syncthreads();
    // ---- prev correction + new_info + z update ----
    {
      f4v accp = {0, 0, 0, 0};
#pragma unroll
      for (int ks = 0; ks < 4; ks++) {
        s8v ak = *(const s8v*)&k_bf[m * 136 + ks * 32 + q * 8];
        s8v bm = *(const s8v*)&Wbf[(wv * 16 + m) * 132 + ks * 32 + q * 8];
        accp = __builtin_amdgcn_mfma_f32_16x16x32_bf16(ak, bm, accp, 0, 0, 0);
      }
#pragma unroll
      for (int i = 0; i < 4; i++) {
        int r = q * 4 + i;
        float prev = accp[i] * frcp(kden_l[r]);
        float g = fast_sigmoid(accg[i] + bmb);
        ni_lds[r * 65 + wv * 16 + m] = g * (accv[i] - prev);
      }
      if (t < 128) {
        float ssum = 0.f;
#pragma unroll
        for (int r = 0; r < 16; r++) ssum += k_f[r * 128 + t];
        z_l[t] += ssum;
        if (s < 7) zh[(s + 1) * 512 + b * 128 + t] = z_l[t];
      }
    }
    __syncthreads();
    // ---- phase 4: W += k^T @ ni; dump hist[s+1]; prefetch next phase A ----
    {
      int cl = t & 63, kg = t >> 6;
      float niv[16];
#pragma unroll
      for (int mm = 0; mm < 16; mm++) niv[mm] = ni_lds[mm * 65 + cl];
      float delta[32];
#pragma unroll
      for (int jj = 0; jj < 32; jj++) delta[jj] = 0.f;
#pragma unroll
      for (int mm = 0; mm < 16; mm++) {
        const float* kb = &k_f[mm * 128 + kg * 32];
        float nv = niv[mm];
#pragma unroll
        for (int ch = 0; ch < 8; ch++) {
          f4v kv4 = *(const f4v*)(kb + ch * 4);
#pragma unroll
          for (int jj = 0; jj < 4; jj++) delta[ch * 4 + jj] += kv4[jj] * nv;
        }
      }
      unsigned short* hdst = hist + (size_t)(s + 1) * 524288 +
                             ((size_t)b * 1024 + ct * 64 + cl) * 128 + kg * 32;
#pragma unroll
      for (int c8 = 0; c8 < 4; c8++) {
        s8v pk;
#pragma unroll
        for (int u = 0; u < 8; u++) {
          int kk = kg * 32 + c8 * 8 + u;
          float nv = Wf[kk * 64 + cl] + delta[c8 * 8 + u];
          Wf[kk * 64 + cl] = nv;
          pk[u] = (short)f2bf(nv);
        }
        *(s8v*)&Wbf[cl * 132 + kg * 32 + c8 * 8] = pk;
        if (s < 7) *(s8v*)(hdst + c8 * 8) = pk;
      }
      if (s < 7) {
        const unsigned short* qp = Qb + ((size_t)b * 4224 + (s + 1) * 528 + 512 + m) * 128;
#pragma unroll
        for (int ks = 0; ks < 4; ks++) aq[ks] = *(const s8v*)(qp + ks * 32 + q * 8);
        const float* mop = MO + ((size_t)b * 4224 + (s + 1) * 528 + 512 + q * 4) * 1024 + col;
#pragma unroll
        for (int i = 0; i < 4; i++) mo_pf[i] = mop[(size_t)i * 1024];
      }
    }
    __syncthreads();
  }
}

// ------ deferred bulk assoc: 64x64 tiles, float4 MO/OUT epilogue -------------
__global__ __launch_bounds__(256) void a_bulk_kernel(
    const unsigned short* __restrict__ Qb, const unsigned short* __restrict__ hist,
    const float* __restrict__ zh, const float* __restrict__ MO,
    float* __restrict__ OUT) {
  __shared__ float as_l[64 * 65];
  int t = threadIdx.x, wv = t >> 6, lane = t & 63, m = lane & 15, q = lane >> 4;
  int rt4 = blockIdx.x, ct = blockIdx.y;
  int seg = blockIdx.z >> 2, b = blockIdx.z & 3;
  const unsigned short* Wm = hist + (size_t)seg * 524288 + ((size_t)b * 1024 + ct * 64) * 128;
  const float* zp = zh + seg * 512 + b * 128;
  size_t grow = (size_t)b * 4224 + seg * 528 + rt4 * 64 + wv * 16;
  const unsigned short* qp = Qb + (grow + m) * 128;
  s8v a[4];
  float dp = 0.f;
#pragma unroll
  for (int ks = 0; ks < 4; ks++) {
    a[ks] = *(const s8v*)(qp + ks * 32 + q * 8);
    f4v z0 = *(const f4v*)(zp + ks * 32 + q * 8);
    f4v z1 = *(const f4v*)(zp + ks * 32 + q * 8 + 4);
#pragma unroll
    for (int j = 0; j < 4; j++) dp += bf2f((unsigned short)a[ks][j]) * z0[j];
#pragma unroll
    for (int j = 0; j < 4; j++) dp += bf2f((unsigned short)a[ks][j + 4]) * z1[j];
  }
  dp += __shfl_xor(dp, 16);
  dp += __shfl_xor(dp, 32);
  dp += EPS;
  f4v acc[4] = {f4v{0,0,0,0}, f4v{0,0,0,0}, f4v{0,0,0,0}, f4v{0,0,0,0}};
#pragma unroll
  for (int ks = 0; ks < 4; ks++) {
#pragma unroll
    for (int nf = 0; nf < 4; nf++) {
      s8v bv = *(const s8v*)(Wm + (size_t)(nf * 16 + m) * 128 + ks * 32 + q * 8);
      acc[nf] = __builtin_amdgcn_mfma_f32_16x16x32_bf16(a[ks], bv, acc[nf], 0, 0, 0);
    }
  }
#pragma unroll
  for (int i = 0; i < 4; i++) {
    float rden = frcp(__shfl(dp, q * 4 + i));
#pragma unroll
    for (int nf = 0; nf < 4; nf++)
      as_l[(wv * 16 + q * 4 + i) * 65 + nf * 16 + m] = acc[nf][i] * rden;
  }
  __syncthreads();
  {
    int r = t >> 2, cchunk = (t & 3) * 16;
    size_t rbase = ((size_t)b * 4224 + seg * 528 + rt4 * 64 + r) * 1024 + ct * 64 + cchunk;
    const float* ar = &as_l[r * 65 + cchunk];
#pragma unroll
    for (int u = 0; u < 4; u++) {
      f4v mo = *(const f4v*)(MO + rbase + u * 4);
      f4v o;
#pragma unroll
      for (int j = 0; j < 4; j++) o[j] = mo[j] + fast_tanh(ar[u * 4 + j]);
      *(f4v*)(OUT + rbase + u * 4) = o;
    }
  }
}

extern "C" void kernel_launch(void* const* d_in, const int* in_sizes, int n_in,
                              void* d_out, int out_size, void* d_ws, size_t ws_size,
                              hipStream_t stream) {
  const float* HS  = (const float*)d_in[0];
  const float* MO  = (const float*)d_in[1];
  const float* W_mq = (const float*)d_in[2];
  const float* W_mk = (const float*)d_in[3];
  const float* W_mv = (const float*)d_in[4];
  const float* W_mb = (const float*)d_in[5];
  const float* b_mb = (const float*)d_in[6];
  float* OUT = (float*)d_out;

  char* wsb = (char*)d_ws;
  unsigned short* hist   = (unsigned short*)(wsb + 0);        // 8 x 1,048,576
  float*          zh     = (float*)(wsb + 8388608);           // 8 x 2,048
  unsigned short* Qb     = (unsigned short*)(wsb + 8404992);  // 4,325,376
  unsigned short* W_mqT  = (unsigned short*)(wsb + 12730368); // 131,072
  unsigned short* W_mkT  = (unsigned short*)(wsb + 12861440); // 131,072
  unsigned short* W_mvT  = (unsigned short*)(wsb + 12992512); // 2,097,152
  unsigned short* W_mbT  = (unsigned short*)(wsb + 15089664); // 2,097,152
  unsigned short* mem_bf = (unsigned short*)(wsb + 17186816); // 2 x 131,072
  int*            bar    = (int*)(wsb + 17448960);            // 128 B
  // total ~17.45 MB

  (void)hipMemsetAsync(wsb, 0, 1048576, stream);            // hist slot 0
  (void)hipMemsetAsync(wsb + 8388608, 0, 2048, stream);     // zh slot 0
  (void)hipMemsetAsync(bar, 0, 128, stream);
  transpose_kernel<<<2176, 256, 0, stream>>>(W_mq, W_mk, W_mv, W_mb,
                                             W_mqT, W_mkT, W_mvT, W_mbT);
  q_kernel<<<1056, 128, 0, stream>>>(HS, W_mqT, Qb);
  scan_kernel<<<64, 256, 0, stream>>>(Qb, W_mkT, W_mvT, W_mbT, b_mb, MO, OUT,
                                      hist, zh, mem_bf, bar);
  a_bulk_kernel<<<dim3(8, 16, 32), 256, 0, stream>>>(Qb, hist, zh, MO, OUT);
}